// Round 1
// 290.293 us; speedup vs baseline: 1.0190x; 1.0190x over previous
//
#include <hip/hip_runtime.h>
#include <hip/hip_bf16.h>
#include <cstdint>
#include <cstddef>

// K(x,y) = exp(-0.5*||x-y||^2) + 0.1*(x.y^T + 1)^3
// x,y: (8192, 256) fp32. out: (8192, 8192) fp32.
//
// bf16 MFMA GEMM (128x128 tile, BK=64, global_load_lds width=16) with fused
// epilogue. LDS fragment reads are XOR-swizzled (slot ^= row&7) to kill the
// 8-way bank conflict of the row-major layout; per rule #21 the swizzle is
// applied on BOTH sides: pre-swizzled per-lane GLOBAL source addresses
// (LDS dest stays linear, as global_load_lds requires) + swizzled ds_read.

#define NROWS 8192
#define DK    256
#define BM    128
#define BN    128
#define BK    64

typedef __bf16 bf16_8 __attribute__((ext_vector_type(8)));
typedef float  f32x4  __attribute__((ext_vector_type(4)));

__device__ __forceinline__ unsigned short f2bf(float f) {
    unsigned int u = __builtin_bit_cast(unsigned int, f);
    u = (u + 0x7FFFu + ((u >> 16) & 1u)) >> 16;  // round-to-nearest-even
    return (unsigned short)u;
}

// ---------------------------------------------------------------------------
// Prep: fp32 -> bf16 conversion + row squared-norms (fp32, exact-ish).
// One wave per row pair (x row b, y row b). 8192 blocks x 64 threads.
// ---------------------------------------------------------------------------
__global__ __launch_bounds__(64) void prep_kernel(
    const float* __restrict__ x, const float* __restrict__ y,
    unsigned short* __restrict__ xb, unsigned short* __restrict__ yb,
    float* __restrict__ x2, float* __restrict__ y2)
{
    const int row  = blockIdx.x;
    const int lane = threadIdx.x;          // 0..63, 4 floats each = 256
    const size_t base = (size_t)row * DK + lane * 4;

    const float4 vx = *(const float4*)(x + base);
    const float4 vy = *(const float4*)(y + base);

    ushort4 hx = make_ushort4(f2bf(vx.x), f2bf(vx.y), f2bf(vx.z), f2bf(vx.w));
    ushort4 hy = make_ushort4(f2bf(vy.x), f2bf(vy.y), f2bf(vy.z), f2bf(vy.w));
    *(ushort4*)(xb + base) = hx;
    *(ushort4*)(yb + base) = hy;

    float sx = vx.x * vx.x + vx.y * vx.y + vx.z * vx.z + vx.w * vx.w;
    float sy = vy.x * vy.x + vy.y * vy.y + vy.z * vy.z + vy.w * vy.w;
    #pragma unroll
    for (int off = 32; off > 0; off >>= 1) {
        sx += __shfl_down(sx, off);
        sy += __shfl_down(sy, off);
    }
    if (lane == 0) {
        x2[row] = sx;
        y2[row] = sy;
    }
}

// ---------------------------------------------------------------------------
// GEMM + fused epilogue. C = x_bf @ y_bf^T with 16x16x32 bf16 MFMA.
// Block = 256 threads = 4 waves in 2x2, each wave owns a 64x64 sub-tile
// (4x4 grid of 16x16 MFMA tiles). Single-buffered LDS (32 KB), BK=64:
// 4 K-iterations, 2 barriers each (half the barrier drains of BK=32).
//
// LDS tile layout: [128 rows][8 slots of 16B] per operand. Swizzle: LDS slot
// s of row r holds GLOBAL slot s ^ (r&7). Staging (linear LDS dest): within a
// 1-KiB chunk (8 rows), lane l -> row (l>>3), LDS slot (l&7), so its global
// source slot is (l&7) ^ (l>>3). Fragment read for global slot g of row r
// reads LDS slot g ^ (r&7): lanes 0..15 (rows r..r+15) then touch all 8 bank
// groups -> 2-way residual aliasing = free (m136).
// ---------------------------------------------------------------------------
__global__ __launch_bounds__(256) void gemm_ep_kernel(
    const unsigned short* __restrict__ xb, const unsigned short* __restrict__ yb,
    const float* __restrict__ x2, const float* __restrict__ y2,
    float* __restrict__ out)
{
    __shared__ __align__(16) unsigned short As[BM * BK];  // 16 KB
    __shared__ __align__(16) unsigned short Bs[BN * BK];  // 16 KB

    const int tid  = threadIdx.x;
    const int wave = tid >> 6;
    const int lane = tid & 63;
    const int bm   = blockIdx.x;
    const int bn   = blockIdx.y;

    const int wm = (wave & 1) * 64;   // wave's row offset in 128-tile
    const int wn = (wave >> 1) * 64;  // wave's col offset in 128-tile

    // --- staging: tile is 128 rows x 64 cols bf16 = 16 KB = 16 chunks of
    // 1 KiB. Wave w stages chunks 4w..4w+3 of A and B (8 global_load_lds).
    const int subrow = lane >> 3;                 // 0..7 row within chunk
    const int sslot  = (lane & 7) ^ subrow;       // pre-swizzled global slot
    const size_t laneoff = (size_t)subrow * DK + sslot * 8;

    const unsigned short* gA[4];
    const unsigned short* gB[4];
    unsigned short* lA[4];
    unsigned short* lB[4];
    #pragma unroll
    for (int m = 0; m < 4; ++m) {
        const int c = wave * 4 + m;               // chunk id, rows c*8..c*8+7
        gA[m] = xb + (size_t)(bm * BM + c * 8) * DK + laneoff;
        gB[m] = yb + (size_t)(bn * BN + c * 8) * DK + laneoff;
        lA[m] = &As[c * 512];                     // 512 ushort = 1 KiB
        lB[m] = &Bs[c * 512];
    }

    f32x4 acc[4][4];
    #pragma unroll
    for (int i = 0; i < 4; ++i)
        #pragma unroll
        for (int j = 0; j < 4; ++j)
            acc[i][j] = (f32x4){0.f, 0.f, 0.f, 0.f};

    const int quad = lane >> 4;   // 0..3
    const int l15  = lane & 15;
    const int l7   = l15 & 7;     // == row&7 for every fragment row we read

    const int rbaseA = (wm + l15) * BK;   // ushort index of row start
    const int rbaseB = (wn + l15) * BK;

    #pragma unroll
    for (int kt = 0; kt < DK; kt += BK) {
        #pragma unroll
        for (int m = 0; m < 4; ++m) {
            __builtin_amdgcn_global_load_lds(
                (const __attribute__((address_space(1))) void*)(gA[m] + kt),
                (__attribute__((address_space(3))) void*)lA[m], 16, 0, 0);
            __builtin_amdgcn_global_load_lds(
                (const __attribute__((address_space(1))) void*)(gB[m] + kt),
                (__attribute__((address_space(3))) void*)lB[m], 16, 0, 0);
        }
        __syncthreads();

        // Two K-steps of 32 from this 64-wide tile.
        #pragma unroll
        for (int kk = 0; kk < 2; ++kk) {
            const int slot = ((kk << 2) | quad) ^ l7;   // swizzled 16-B slot
            bf16_8 afr[4], bfr[4];
            #pragma unroll
            for (int i = 0; i < 4; ++i)
                afr[i] = *(const bf16_8*)&As[rbaseA + i * 16 * BK + slot * 8];
            #pragma unroll
            for (int j = 0; j < 4; ++j)
                bfr[j] = *(const bf16_8*)&Bs[rbaseB + j * 16 * BK + slot * 8];

            #pragma unroll
            for (int i = 0; i < 4; ++i)
                #pragma unroll
                for (int j = 0; j < 4; ++j)
                    acc[i][j] = __builtin_amdgcn_mfma_f32_16x16x32_bf16(
                        afr[i], bfr[j], acc[i][j], 0, 0, 0);
        }
        __syncthreads();
    }

    // --- epilogue. C/D layout (verified m89/m91): col = lane&15, row = quad*4+reg
    const int mBase = bm * BM + wm + quad * 4;
    const int nBase = bn * BN + wn + l15;

    float y2v[4];
    #pragma unroll
    for (int j = 0; j < 4; ++j) y2v[j] = y2[nBase + j * 16];

    #pragma unroll
    for (int i = 0; i < 4; ++i) {
        #pragma unroll
        for (int r = 0; r < 4; ++r) {
            const int m = mBase + i * 16 + r;
            const float xv = x2[m];
            float* orow = out + (size_t)m * NROWS + nBase;
            #pragma unroll
            for (int j = 0; j < 4; ++j) {
                const float xy = acc[i][j][r];
                float s = xv + y2v[j] - 2.0f * xy;
                s = fmaxf(s, 0.0f);
                const float e = __expf(-0.5f * s);
                const float p = xy + 1.0f;
                orow[j * 16] = fmaf(0.1f, p * p * p, e);
            }
        }
    }
}

// ---------------------------------------------------------------------------
extern "C" void kernel_launch(void* const* d_in, const int* in_sizes, int n_in,
                              void* d_out, int out_size, void* d_ws, size_t ws_size,
                              hipStream_t stream) {
    const float* x = (const float*)d_in[0];
    const float* y = (const float*)d_in[1];
    float* out = (float*)d_out;

    char* ws = (char*)d_ws;
    unsigned short* xb = (unsigned short*)ws;                                  // 4 MB
    unsigned short* yb = (unsigned short*)(ws + (size_t)NROWS * DK * 2);       // 4 MB
    float* x2 = (float*)(ws + (size_t)2 * NROWS * DK * 2);                     // 32 KB
    float* y2 = x2 + NROWS;                                                    // 32 KB

    prep_kernel<<<NROWS, 64, 0, stream>>>(x, y, xb, yb, x2, y2);

    dim3 grid(NROWS / BM, NROWS / BN);
    gemm_ep_kernel<<<grid, 256, 0, stream>>>(xb, yb, x2, y2, out);
}